// Round 10
// baseline (103.679 us; speedup 1.0000x reference)
//
#include <hip/hip_runtime.h>

#define N_STATE 512
#define N_HEAD 8
#define HEAD_DIM 64
#define KV_LEN 32768
#define T_TOTAL 32769

typedef float v4f __attribute__((ext_vector_type(4)));

// d_out layout (float offsets)
#define QK_OFF 512
#define K_OFF (512 + N_HEAD * T_TOTAL)
#define V_OFF (K_OFF + (size_t)T_TOTAL * N_STATE)

// d_ws layout (float offsets)
#define WS_Q 0
#define WS_K 512
#define WS_V 1024
#define WS_LF 1544       // 8: final per-head denom
#define WS_WN 1552       // 8: weight of the new row
#define WS_WV 1600       // 512: attention output (pre out-proj)
#define WS_PL 6272       // NBLK*8 per-block sumexp (1024*8 ends at 14464 < 14848)
#define WS_PART 14848    // NBLK*512 partial acc, then RB2*512 part2
#define NBLK 1024        // kread grid
#define RB2 32

// ---------------------------------------------------------------------------
// Kernel A: q = x@wq.T + bq ; k_new = x@wk.T ; v_new = x@wv.T + bv
// ---------------------------------------------------------------------------
__global__ void proj_kernel(const float* __restrict__ x,
                            const float* __restrict__ wq, const float* __restrict__ bq,
                            const float* __restrict__ wk,
                            const float* __restrict__ wv, const float* __restrict__ bv,
                            float* __restrict__ ws, float* __restrict__ out)
{
    int o = blockIdx.x * 256 + threadIdx.x;      // 0..1535
    int which = o >> 9;
    int idx   = o & 511;
    const float* W = (which == 0) ? wq : (which == 1) ? wk : wv;
    const float4* Wr = (const float4*)(W + (size_t)idx * N_STATE);
    const float4* xv = (const float4*)x;
    float s = 0.f;
#pragma unroll 8
    for (int j = 0; j < N_STATE / 4; ++j) {
        float4 a = xv[j], b = Wr[j];
        s += a.x * b.x + a.y * b.y + a.z * b.z + a.w * b.w;
    }
    if (which == 0) {
        s += bq[idx];
        ws[WS_Q + idx] = s;
    } else if (which == 1) {
        ws[WS_K + idx] = s;
        out[K_OFF + (size_t)KV_LEN * N_STATE + idx] = s;   // new k row
    } else {
        s += bv[idx];
        ws[WS_V + idx] = s;
        out[V_OFF + (size_t)KV_LEN * N_STATE + idx] = s;   // new v row
    }
}

// ---------------------------------------------------------------------------
// Kernel B (kread): READ-ONLY streaming pass.  Reads kc+vc (128 MB, fits the
// 256 MB MALL), computes qk logits + exp-weighted partial sums.  Writes only
// ~3 MB (qk logits + per-block partials).  HBM traffic is essentially
// unidirectional (read) -> measures the machine's pure-read ceiling, and
// leaves kc/vc MALL-resident for the copy kernel.
// Wave-per-row dense front: wave wid handles rows r = s*8192 + wid.
// Lane l holds floats 8l..8l+7 of a row; head = l>>3.
// ---------------------------------------------------------------------------
__global__ void __launch_bounds__(512, 4)
kread_kernel(const float* __restrict__ kc, const float* __restrict__ vc,
             const float* __restrict__ ws_ro, float* __restrict__ out,
             float* __restrict__ part, float* __restrict__ pl)
{
    int tid  = threadIdx.x;
    int lane = tid & 63;
    int w    = tid >> 6;
    int wid  = blockIdx.x * 8 + w;     // 0..8191
    int h    = lane >> 3;
    const v4f* kc4 = (const v4f*)kc;
    const v4f* vc4 = (const v4f*)vc;
    float* qkout = out + QK_OFF;

    v4f q0 = ((const v4f*)(ws_ro + WS_Q))[2 * lane]     * 0.125f;
    v4f q1 = ((const v4f*)(ws_ro + WS_Q))[2 * lane + 1] * 0.125f;

    v4f a0 = (v4f)0.f, a1 = (v4f)0.f;
    float lsum = 0.f;

#pragma unroll
    for (int s = 0; s < 4; ++s) {
        int r = s * (NBLK * 8) + wid;
        size_t b = (size_t)r * 128 + 2 * lane;
        v4f k0 = kc4[b], k1 = kc4[b + 1];
        v4f v0 = vc4[b], v1 = vc4[b + 1];
        float p = k0.x * q0.x + k0.y * q0.y + k0.z * q0.z + k0.w * q0.w
                + k1.x * q1.x + k1.y * q1.y + k1.z * q1.z + k1.w * q1.w;
        p += __shfl_xor(p, 1);
        p += __shfl_xor(p, 2);
        p += __shfl_xor(p, 4);
        if ((lane & 7) == 0) qkout[(size_t)h * T_TOTAL + r] = p;
        float wgt = __expf(p);
        lsum += wgt;
        a0 += wgt * v0;
        a1 += wgt * v1;
    }

    // fold the 8 waves of this block -> part[block][512], pl[block][8]
    __shared__ v4f ldsacc[8][128];
    __shared__ float sl[8][8];
    ldsacc[w][2 * lane]     = a0;
    ldsacc[w][2 * lane + 1] = a1;
    if ((lane & 7) == 0) sl[w][h] = lsum;
    __syncthreads();
    if (tid < 128) {
        v4f s4 = (v4f)0.f;
#pragma unroll
        for (int ww = 0; ww < 8; ++ww) s4 += ldsacc[ww][tid];
        ((v4f*)(part + (size_t)blockIdx.x * N_STATE))[tid] = s4;
    } else if (tid < 136) {
        int hh = tid - 128;
        float s = 0.f;
#pragma unroll
        for (int ww = 0; ww < 8; ++ww) s += sl[ww][hh];
        pl[blockIdx.x * N_HEAD + hh] = s;
    }
}

// ---------------------------------------------------------------------------
// Kernel C (copy): pure copy kc->kout, vc->vout.  Reads should be MALL-hot
// (kread just streamed both inputs), so HBM sees essentially write-only
// traffic -- the 7.1 TB/s regime.  NT stores avoid allocating the written
// lines in MALL, preserving kc/vc residency for the next replay.
// 2048 blocks x 256 threads, grid-stride, batched 4-load/4-store groups.
// ---------------------------------------------------------------------------
#define COPY_THREADS (2048 * 256)            // 524288; 4194304/524288 = 8 strides
__global__ void __launch_bounds__(256)
copy_kernel(const float* __restrict__ kc, const float* __restrict__ vc,
            float* __restrict__ out)
{
    size_t gid = (size_t)blockIdx.x * 256 + threadIdx.x;
    const v4f* kc4 = (const v4f*)kc;
    const v4f* vc4 = (const v4f*)vc;
    v4f* kout4 = (v4f*)(out + K_OFF);
    v4f* vout4 = (v4f*)(out + V_OFF);
#pragma unroll
    for (int j = 0; j < 2; ++j) {
        size_t i0 = (size_t)(4 * j + 0) * COPY_THREADS + gid;
        size_t i1 = (size_t)(4 * j + 1) * COPY_THREADS + gid;
        size_t i2 = (size_t)(4 * j + 2) * COPY_THREADS + gid;
        size_t i3 = (size_t)(4 * j + 3) * COPY_THREADS + gid;
        v4f t0 = kc4[i0], t1 = kc4[i1], t2 = kc4[i2], t3 = kc4[i3];
        __builtin_nontemporal_store(t0, &kout4[i0]);
        __builtin_nontemporal_store(t1, &kout4[i1]);
        __builtin_nontemporal_store(t2, &kout4[i2]);
        __builtin_nontemporal_store(t3, &kout4[i3]);
    }
#pragma unroll
    for (int j = 0; j < 2; ++j) {
        size_t i0 = (size_t)(4 * j + 0) * COPY_THREADS + gid;
        size_t i1 = (size_t)(4 * j + 1) * COPY_THREADS + gid;
        size_t i2 = (size_t)(4 * j + 2) * COPY_THREADS + gid;
        size_t i3 = (size_t)(4 * j + 3) * COPY_THREADS + gid;
        v4f t0 = vc4[i0], t1 = vc4[i1], t2 = vc4[i2], t3 = vc4[i3];
        __builtin_nontemporal_store(t0, &vout4[i0]);
        __builtin_nontemporal_store(t1, &vout4[i1]);
        __builtin_nontemporal_store(t2, &vout4[i2]);
        __builtin_nontemporal_store(t3, &vout4[i3]);
    }
}

// ---------------------------------------------------------------------------
// Kernel D (mstats): per head, global denom across blocks + new-row logit.
// ---------------------------------------------------------------------------
__global__ void mstats_kernel(float* __restrict__ ws, float* __restrict__ out, int nblk)
{
    int h = blockIdx.x;
    int j = threadIdx.x;
    const float* pl = ws + WS_PL;

    float lg = 0.f;
    for (int b = j; b < nblk; b += 64) lg += pl[b * N_HEAD + h];
    for (int off = 32; off >= 1; off >>= 1) lg += __shfl_xor(lg, off);

    float p = ws[WS_Q + h * 64 + j] * ws[WS_K + h * 64 + j];
    for (int off = 32; off >= 1; off >>= 1) p += __shfl_xor(p, off);
    p *= 0.125f;

    if (j == 0) {
        float wn = __expf(p);
        out[QK_OFF + (size_t)h * T_TOTAL + KV_LEN] = p;
        ws[WS_LF + h] = lg + wn;
        ws[WS_WN + h] = wn;
    }
}

// ---------------------------------------------------------------------------
// Kernel E: fold NBLK acc rows -> RB2 rows (pure sum, coalesced float4).
// ---------------------------------------------------------------------------
__global__ void reduce1_kernel(const float* __restrict__ part,
                               float* __restrict__ part2, int rpb)
{
    int c4 = threadIdx.x & 127;
    int rg = threadIdx.x >> 7;
    int hrpb = rpb >> 1;
    int r0 = blockIdx.x * rpb + rg * hrpb;
    float4 acc = {0.f, 0.f, 0.f, 0.f};
    for (int r = 0; r < hrpb; ++r) {
        float4 p = ((const float4*)(part + (size_t)(r0 + r) * N_STATE))[c4];
        acc.x += p.x; acc.y += p.y; acc.z += p.z; acc.w += p.w;
    }
    __shared__ float4 sacc[128];
    if (rg == 1) sacc[c4] = acc;
    __syncthreads();
    if (rg == 0) {
        float4 o = sacc[c4];
        acc.x += o.x; acc.y += o.y; acc.z += o.z; acc.w += o.w;
        ((float4*)(part2 + (size_t)blockIdx.x * N_STATE))[c4] = acc;
    }
}

// ---------------------------------------------------------------------------
// Kernel F: final fold + new-row term + divide. 8 blocks x 64 threads.
// ---------------------------------------------------------------------------
__global__ void reduce2_kernel(float* __restrict__ ws, const float* __restrict__ part2)
{
    int h = blockIdx.x;
    int c = h * 64 + threadIdx.x;
    float s = 0.f;
    for (int b = 0; b < RB2; ++b) s += part2[(size_t)b * N_STATE + c];
    s += ws[WS_WN + h] * ws[WS_V + c];
    ws[WS_WV + c] = s / ws[WS_LF + h];
}

// ---------------------------------------------------------------------------
// Kernel G: out = wv_ @ wo.T + bo. 32 blocks x 256 threads (16 outputs/blk).
// ---------------------------------------------------------------------------
__global__ void outproj_kernel(const float* __restrict__ ws, const float* __restrict__ wo,
                               const float* __restrict__ bo, float* __restrict__ out)
{
    int r    = blockIdx.x * 16 + (threadIdx.x >> 4);
    int lane = threadIdx.x & 15;
    const float4* wr  = (const float4*)(wo + (size_t)r * N_STATE);
    const float4* wv4 = (const float4*)(ws + WS_WV);
    float s = 0.f;
#pragma unroll
    for (int k = 0; k < 8; ++k) {
        int c4 = lane + k * 16;
        float4 a = wv4[c4], b = wr[c4];
        s += a.x * b.x + a.y * b.y + a.z * b.z + a.w * b.w;
    }
    s += __shfl_xor(s, 1);
    s += __shfl_xor(s, 2);
    s += __shfl_xor(s, 4);
    s += __shfl_xor(s, 8);
    if (lane == 0) out[r] = s + bo[r];
}

extern "C" void kernel_launch(void* const* d_in, const int* in_sizes, int n_in,
                              void* d_out, int out_size, void* d_ws, size_t ws_size,
                              hipStream_t stream)
{
    const float* x  = (const float*)d_in[0];
    const float* kc = (const float*)d_in[1];
    const float* vc = (const float*)d_in[2];
    const float* wq = (const float*)d_in[3];
    const float* bq = (const float*)d_in[4];
    const float* wk = (const float*)d_in[5];
    const float* wv = (const float*)d_in[6];
    const float* bv = (const float*)d_in[7];
    const float* wo = (const float*)d_in[8];
    const float* bo = (const float*)d_in[9];
    float* out = (float*)d_out;
    float* ws  = (float*)d_ws;

    float* part  = ws + WS_PART;
    float* part2 = part + (size_t)NBLK * N_STATE;
    float* pl    = ws + WS_PL;

    hipLaunchKernelGGL(proj_kernel, dim3(6), dim3(256), 0, stream,
                       x, wq, bq, wk, wv, bv, ws, out);
    hipLaunchKernelGGL(kread_kernel, dim3(NBLK), dim3(512), 0, stream,
                       kc, vc, ws, out, part, pl);
    hipLaunchKernelGGL(copy_kernel, dim3(2048), dim3(256), 0, stream,
                       kc, vc, out);
    hipLaunchKernelGGL(mstats_kernel, dim3(8), dim3(64), 0, stream, ws, out, NBLK);
    hipLaunchKernelGGL(reduce1_kernel, dim3(RB2), dim3(256), 0, stream,
                       part, part2, NBLK / RB2);
    hipLaunchKernelGGL(reduce2_kernel, dim3(8), dim3(64), 0, stream, ws, part2);
    hipLaunchKernelGGL(outproj_kernel, dim3(32), dim3(256), 0, stream, ws, wo, bo, out);
}

// Round 11
// 84.927 us; speedup vs baseline: 1.2208x; 1.2208x over previous
//
#include <hip/hip_runtime.h>

#define N_STATE 512
#define N_HEAD 8
#define HEAD_DIM 64
#define KV_LEN 32768
#define T_TOTAL 32769

typedef float v4f __attribute__((ext_vector_type(4)));

// d_out layout (float offsets)
#define QK_OFF 512
#define K_OFF (512 + N_HEAD * T_TOTAL)            // 262664 floats -> f4 65666
#define V_OFF (K_OFF + (size_t)T_TOTAL * N_STATE) // 17040392 floats -> f4 4260098
// f4-index maps: out_f4(src_f4 s) = s + 65666 (K), s + 4260098 (V).
// Both are ==2 (mod 8): aligned store grid = s + 65664 / s + 4260096.
#define KOUT_F4 65666
#define VOUT_F4 4260098
#define KOUT_AL 65664
#define VOUT_AL 4260096

// d_ws layout (float offsets)
#define WS_Q 0
#define WS_K 512
#define WS_V 1024
#define WS_WV 1600       // 512: attention output (pre out-proj)
#define WS_PL 6272       // nblk*8 per-block sumexp (max 1024*8 = 8192)
#define WS_PART 14848    // nblk*512 partial acc, then RB2*512 part2
#define NBLK_MAX 1024
#define RB2 32

// ---------------------------------------------------------------------------
// Kernel A: q = x@wq.T + bq ; k_new = x@wk.T ; v_new = x@wv.T + bv
// ---------------------------------------------------------------------------
__global__ void proj_kernel(const float* __restrict__ x,
                            const float* __restrict__ wq, const float* __restrict__ bq,
                            const float* __restrict__ wk,
                            const float* __restrict__ wv, const float* __restrict__ bv,
                            float* __restrict__ ws, float* __restrict__ out)
{
    int o = blockIdx.x * 256 + threadIdx.x;      // 0..1535
    int which = o >> 9;
    int idx   = o & 511;
    const float* W = (which == 0) ? wq : (which == 1) ? wk : wv;
    const float4* Wr = (const float4*)(W + (size_t)idx * N_STATE);
    const float4* xv = (const float4*)x;
    float s = 0.f;
#pragma unroll 8
    for (int j = 0; j < N_STATE / 4; ++j) {
        float4 a = xv[j], b = Wr[j];
        s += a.x * b.x + a.y * b.y + a.z * b.z + a.w * b.w;
    }
    if (which == 0) {
        s += bq[idx];
        ws[WS_Q + idx] = s;
    } else if (which == 1) {
        ws[WS_K + idx] = s;
        out[K_OFF + (size_t)KV_LEN * N_STATE + idx] = s;   // new k row
    } else {
        s += bv[idx];
        ws[WS_V + idx] = s;
        out[V_OFF + (size_t)KV_LEN * N_STATE + idx] = s;   // new v row
    }
}

// ---------------------------------------------------------------------------
// Kernel B (fused stream): R6 structure (best measured standalone) with ONE
// change: NON-TEMPORAL LOADS on kc/vc.  Theory: d_out's previous-replay dirty
// lines occupy the write-back MALL; read-allocations evict them early (extra
// writeback), then our stores re-dirty fresh lines (second writeback).
// NT loads don't allocate -> dirt stays resident until our stores merge into
// it -> per-replay HBM drops from ~R+2W to ~R+W.
// ---------------------------------------------------------------------------
__global__ void __launch_bounds__(512, 4)
stream_kernel(const float* __restrict__ kc, const float* __restrict__ vc,
              const float* __restrict__ ws_ro,
              float* __restrict__ out,
              float* __restrict__ part, float* __restrict__ pl, int rows_per_blk)
{
    int tid = threadIdx.x;
    int i   = tid & 127;       // float4 column index (0..127)
    int rg  = tid >> 7;        // row group (0..3)
    int h   = i >> 4;          // head (0..7)
    v4f q4 = ((const v4f*)(ws_ro + WS_Q))[i];
    q4 *= 0.125f;              // scale^2
    const v4f* kc4 = (const v4f*)kc;
    const v4f* vc4 = (const v4f*)vc;
    v4f* out4 = (v4f*)out;
    float* qkout = out + QK_OFF;

    __shared__ v4f ldsK[512], ldsV[512];
    __shared__ v4f sacc[3][128];
    __shared__ float sl[3][8];

    float l = 0.f;
    v4f acc = (v4f)0.f;

    int nch = rows_per_blk >> 2;
    size_t cb = (size_t)blockIdx.x * rows_per_blk * 128;   // src f4 chunk base
    int t = blockIdx.x * rows_per_blk + rg;                // this thread's row

    v4f kv = __builtin_nontemporal_load(&kc4[cb + tid]);
    v4f vv = __builtin_nontemporal_load(&vc4[cb + tid]);
    v4f kn = kv, vn = vv;
    v4f stashK = kv, stashV = vv;    // init value irrelevant (first use masked)

    for (int n = 0; n < nch; ++n) {
        if (n + 1 < nch) {                       // depth-1 register prefetch
            kn = __builtin_nontemporal_load(&kc4[cb + 512 + tid]);
            vn = __builtin_nontemporal_load(&vc4[cb + 512 + tid]);
        }
        // ---- compute (row-aligned registers) ----
        float p = kv.x * q4.x + kv.y * q4.y + kv.z * q4.z + kv.w * q4.w;
        p += __shfl_xor(p, 1);
        p += __shfl_xor(p, 2);
        p += __shfl_xor(p, 4);
        p += __shfl_xor(p, 8);
        if ((tid & 15) == 0) qkout[(size_t)h * T_TOTAL + t] = p;
        float w = __expf(p);
        l += w;
        acc += w * vv;

        // ---- aligned copy-out via LDS shift ----
        __syncthreads();                          // prev store-phase reads done
        if (tid >= 510) { ldsK[tid - 510] = stashK; ldsV[tid - 510] = stashV; }
        else            { ldsK[tid + 2]  = kv;     ldsV[tid + 2]  = vv;     }
        __syncthreads();
        v4f sk = ldsK[tid], sv = ldsV[tid];
        if (n | (tid >> 1)) {                     // skip n==0 && tid<2 (prev block's data)
            __builtin_nontemporal_store(sk, &out4[cb + KOUT_AL + tid]);
            __builtin_nontemporal_store(sv, &out4[cb + VOUT_AL + tid]);
        }
        if (tid >= 510) { stashK = kv; stashV = vv; }
        kv = kn; vv = vn;
        cb += 512; t += 4;
    }
    // block tail: last 2 f4 of this block's range, natural (unaligned) address
    if (tid >= 510) {
        size_t s = cb - 512 + tid;                // src f4 B1-2, B1-1
        out4[KOUT_F4 + s] = stashK;
        out4[VOUT_F4 + s] = stashV;
    }

    // ---- merge the four row groups ----
    if (rg != 0) {
        sacc[rg - 1][i] = acc;
        if ((tid & 15) == 0) sl[rg - 1][h] = l;
    }
    __syncthreads();
    if (rg == 0) {
#pragma unroll
        for (int r = 0; r < 3; ++r) acc += sacc[r][i];
        ((v4f*)(part + (size_t)blockIdx.x * N_STATE))[i] = acc;
        if ((tid & 15) == 0)
            pl[blockIdx.x * N_HEAD + h] = l + sl[0][h] + sl[1][h] + sl[2][h];
    }
}

// ---------------------------------------------------------------------------
// Kernel C: fold nblk acc rows -> RB2 rows (pure sum, coalesced float4).
// ---------------------------------------------------------------------------
__global__ void reduce1_kernel(const float* __restrict__ part,
                               float* __restrict__ part2, int rpb)
{
    int c4 = threadIdx.x & 127;
    int rg = threadIdx.x >> 7;
    int hrpb = rpb >> 1;
    int r0 = blockIdx.x * rpb + rg * hrpb;
    float4 acc = {0.f, 0.f, 0.f, 0.f};
    for (int r = 0; r < hrpb; ++r) {
        float4 p = ((const float4*)(part + (size_t)(r0 + r) * N_STATE))[c4];
        acc.x += p.x; acc.y += p.y; acc.z += p.z; acc.w += p.w;
    }
    __shared__ float4 sacc[128];
    if (rg == 1) sacc[c4] = acc;
    __syncthreads();
    if (rg == 0) {
        float4 o = sacc[c4];
        acc.x += o.x; acc.y += o.y; acc.z += o.z; acc.w += o.w;
        ((float4*)(part2 + (size_t)blockIdx.x * N_STATE))[c4] = acc;
    }
}

// ---------------------------------------------------------------------------
// Kernel D (fused mstats + reduce2): ONE block x 512 threads.
// Wave h (= tid>>6) handles head h's denom + new-row logit; then each thread
// owns one of the 512 output columns for the final fold + divide.
// ---------------------------------------------------------------------------
__global__ void mstats2_kernel(float* __restrict__ ws, float* __restrict__ out,
                               const float* __restrict__ part2, int nblk)
{
    int tid = threadIdx.x;
    int h   = tid >> 6;       // 0..7 (== wave index)
    int j   = tid & 63;
    const float* pl = ws + WS_PL;
    __shared__ float slf[8], swn[8];

    float lg = 0.f;
    for (int b = j; b < nblk; b += 64) lg += pl[b * N_HEAD + h];
    for (int off = 32; off >= 1; off >>= 1) lg += __shfl_xor(lg, off);

    float p = ws[WS_Q + h * 64 + j] * ws[WS_K + h * 64 + j];
    for (int off = 32; off >= 1; off >>= 1) p += __shfl_xor(p, off);
    p *= 0.125f;

    if (j == 0) {
        float wn = __expf(p);
        out[QK_OFF + (size_t)h * T_TOTAL + KV_LEN] = p;
        slf[h] = lg + wn;
        swn[h] = wn;
    }
    __syncthreads();

    // reduce2: column c = tid
    int c = tid;
    float s = 0.f;
#pragma unroll
    for (int b = 0; b < RB2; ++b) s += part2[(size_t)b * N_STATE + c];
    s += swn[c >> 6] * ws[WS_V + c];
    ws[WS_WV + c] = s / slf[c >> 6];
}

// ---------------------------------------------------------------------------
// Kernel E: out = wv_ @ wo.T + bo. 32 blocks x 256 threads (16 outputs/blk).
// ---------------------------------------------------------------------------
__global__ void outproj_kernel(const float* __restrict__ ws, const float* __restrict__ wo,
                               const float* __restrict__ bo, float* __restrict__ out)
{
    int r    = blockIdx.x * 16 + (threadIdx.x >> 4);
    int lane = threadIdx.x & 15;
    const float4* wr  = (const float4*)(wo + (size_t)r * N_STATE);
    const float4* wv4 = (const float4*)(ws + WS_WV);
    float s = 0.f;
#pragma unroll
    for (int k = 0; k < 8; ++k) {
        int c4 = lane + k * 16;
        float4 a = wv4[c4], b = wr[c4];
        s += a.x * b.x + a.y * b.y + a.z * b.z + a.w * b.w;
    }
    s += __shfl_xor(s, 1);
    s += __shfl_xor(s, 2);
    s += __shfl_xor(s, 4);
    s += __shfl_xor(s, 8);
    if (lane == 0) out[r] = s + bo[r];
}

extern "C" void kernel_launch(void* const* d_in, const int* in_sizes, int n_in,
                              void* d_out, int out_size, void* d_ws, size_t ws_size,
                              hipStream_t stream)
{
    const float* x  = (const float*)d_in[0];
    const float* kc = (const float*)d_in[1];
    const float* vc = (const float*)d_in[2];
    const float* wq = (const float*)d_in[3];
    const float* bq = (const float*)d_in[4];
    const float* wk = (const float*)d_in[5];
    const float* wv = (const float*)d_in[6];
    const float* bv = (const float*)d_in[7];
    const float* wo = (const float*)d_in[8];
    const float* bo = (const float*)d_in[9];
    float* out = (float*)d_out;
    float* ws  = (float*)d_ws;

    int nblk = NBLK_MAX;
    while (nblk > 64 &&
           (WS_PART + (size_t)(nblk + RB2) * N_STATE) * sizeof(float) > ws_size)
        nblk >>= 1;
    int rows_per_blk = KV_LEN / nblk;
    float* part  = ws + WS_PART;
    float* part2 = part + (size_t)nblk * N_STATE;
    float* pl    = ws + WS_PL;

    hipLaunchKernelGGL(proj_kernel, dim3(6), dim3(256), 0, stream,
                       x, wq, bq, wk, wv, bv, ws, out);
    hipLaunchKernelGGL(stream_kernel, dim3(nblk), dim3(512), 0, stream,
                       kc, vc, ws, out, part, pl, rows_per_blk);
    hipLaunchKernelGGL(reduce1_kernel, dim3(RB2), dim3(256), 0, stream,
                       part, part2, nblk / RB2);
    hipLaunchKernelGGL(mstats2_kernel, dim3(1), dim3(512), 0, stream,
                       ws, out, part2, nblk);
    hipLaunchKernelGGL(outproj_kernel, dim3(32), dim3(256), 0, stream, ws, wo, bo, out);
}

// Round 13
// 84.413 us; speedup vs baseline: 1.2282x; 1.0061x over previous
//
#include <hip/hip_runtime.h>

#define N_STATE 512
#define N_HEAD 8
#define HEAD_DIM 64
#define KV_LEN 32768
#define T_TOTAL 32769

typedef float v4f __attribute__((ext_vector_type(4)));

// d_out layout (float offsets)
#define QK_OFF 512
#define K_OFF (512 + N_HEAD * T_TOTAL)
#define V_OFF (K_OFF + (size_t)T_TOTAL * N_STATE)

// d_ws layout (float offsets)
#define WS_Q 0
#define WS_K 512
#define WS_V 1024
#define WS_WV 1600       // 512: attention output (pre out-proj)
#define WS_PL 6272       // NBLK*8 per-block sumexp
#define WS_PART 14848    // NBLK*512 partial acc, then RB2*512 part2
#define NBLK 1024
#define RPB 32           // rows per block
#define NCH 8            // chunks per block (RPB/4)
#define RB2 32

// ---------------------------------------------------------------------------
// Kernel A: q = x@wq.T + bq ; k_new = x@wk.T ; v_new = x@wv.T + bv
// ---------------------------------------------------------------------------
__global__ void proj_kernel(const float* __restrict__ x,
                            const float* __restrict__ wq, const float* __restrict__ bq,
                            const float* __restrict__ wk,
                            const float* __restrict__ wv, const float* __restrict__ bv,
                            float* __restrict__ ws, float* __restrict__ out)
{
    int o = blockIdx.x * 256 + threadIdx.x;      // 0..1535
    int which = o >> 9;
    int idx   = o & 511;
    const float* W = (which == 0) ? wq : (which == 1) ? wk : wv;
    const float4* Wr = (const float4*)(W + (size_t)idx * N_STATE);
    const float4* xv = (const float4*)x;
    float s = 0.f;
#pragma unroll 8
    for (int j = 0; j < N_STATE / 4; ++j) {
        float4 a = xv[j], b = Wr[j];
        s += a.x * b.x + a.y * b.y + a.z * b.z + a.w * b.w;
    }
    if (which == 0) {
        s += bq[idx];
        ws[WS_Q + idx] = s;
    } else if (which == 1) {
        ws[WS_K + idx] = s;
        out[K_OFF + (size_t)KV_LEN * N_STATE + idx] = s;   // new k row
    } else {
        s += bv[idx];
        ws[WS_V + idx] = s;
        out[V_OFF + (size_t)KV_LEN * N_STATE + idx] = s;   // new v row
    }
}

// ---------------------------------------------------------------------------
// Kernel B (fused stream): barrier-free hot loop (R7 structure).
// NT (non-allocating) LOADS of kc/vc + PLAIN (write-allocating) stores:
// goal is to pin d_out's K/V lines (131 MB) dirty-resident in the 256 MB
// MALL across graph replays (writes never reach HBM), while the 128 MB
// read stream goes HBM->registers without evicting them.  This is the one
// load/store policy combination not yet measured.
// ---------------------------------------------------------------------------
__global__ void __launch_bounds__(512, 8)
stream_kernel(const float* __restrict__ kc, const float* __restrict__ vc,
              const float* __restrict__ ws_ro,
              float* __restrict__ out,
              float* __restrict__ part, float* __restrict__ pl)
{
    int tid = threadIdx.x;
    int i   = tid & 127;       // float4 column index (0..127)
    int rg  = tid >> 7;        // row group (0..3)
    int h   = i >> 4;          // head (0..7)
    v4f q4 = ((const v4f*)(ws_ro + WS_Q))[i];
    q4 *= 0.125f;              // scale^2
    const v4f* kc4 = (const v4f*)kc;
    const v4f* vc4 = (const v4f*)vc;
    v4f* kout4 = (v4f*)(out + K_OFF);
    v4f* vout4 = (v4f*)(out + V_OFF);
    float* qkout = out + QK_OFF;

    float l = 0.f;
    v4f acc = (v4f)0.f;
    float parr[NCH];

    size_t cb = (size_t)blockIdx.x * RPB * 128;
    v4f kv = __builtin_nontemporal_load(&kc4[cb + tid]);
    v4f vv = __builtin_nontemporal_load(&vc4[cb + tid]);
#pragma unroll
    for (int n = 0; n < NCH; ++n) {
        v4f kn, vn;
        if (n + 1 < NCH) {                      // depth-1 register prefetch
            kn = __builtin_nontemporal_load(&kc4[cb + 512 + tid]);
            vn = __builtin_nontemporal_load(&vc4[cb + 512 + tid]);
        }
        kout4[cb + tid] = kv;                    // plain, write-allocating
        vout4[cb + tid] = vv;
        float p = kv.x * q4.x + kv.y * q4.y + kv.z * q4.z + kv.w * q4.w;
        p += __shfl_xor(p, 1);
        p += __shfl_xor(p, 2);
        p += __shfl_xor(p, 4);
        p += __shfl_xor(p, 8);
        parr[n] = p;
        float w = __expf(p);
        l += w;
        acc += w * vv;
        kv = kn; vv = vn;
        cb += 512;
    }

    // ---- epilogue: coalesced qk flush + partial merge (single barrier) ----
    __shared__ float qks[N_HEAD][RPB];
    __shared__ v4f sacc[3][128];
    __shared__ float sl[3][8];
    if ((tid & 15) == 0) {                       // one thread per (rg, h)
#pragma unroll
        for (int n = 0; n < NCH; ++n) qks[h][n * 4 + rg] = parr[n];
        if (rg != 0) sl[rg - 1][h] = l;
    }
    if (rg != 0) sacc[rg - 1][i] = acc;
    __syncthreads();

    int base = blockIdx.x * RPB;
    if (tid < N_HEAD * RPB) {                    // 256 threads: 8 heads x 32 rows
        int hh = tid >> 5, tt = tid & (RPB - 1);
        qkout[(size_t)hh * T_TOTAL + base + tt] = qks[hh][tt];
    }
    if (rg == 0) {
#pragma unroll
        for (int r = 0; r < 3; ++r) acc += sacc[r][i];
        ((v4f*)(part + (size_t)blockIdx.x * N_STATE))[i] = acc;
        if ((tid & 15) == 0)
            pl[blockIdx.x * N_HEAD + h] = l + sl[0][h] + sl[1][h] + sl[2][h];
    }
}

// ---------------------------------------------------------------------------
// Kernel C: fold NBLK acc rows -> RB2 rows (pure sum, coalesced float4).
// ---------------------------------------------------------------------------
__global__ void reduce1_kernel(const float* __restrict__ part,
                               float* __restrict__ part2, int rpb)
{
    int c4 = threadIdx.x & 127;
    int rg = threadIdx.x >> 7;
    int hrpb = rpb >> 1;
    int r0 = blockIdx.x * rpb + rg * hrpb;
    float4 acc = {0.f, 0.f, 0.f, 0.f};
    for (int r = 0; r < hrpb; ++r) {
        float4 p = ((const float4*)(part + (size_t)(r0 + r) * N_STATE))[c4];
        acc.x += p.x; acc.y += p.y; acc.z += p.z; acc.w += p.w;
    }
    __shared__ float4 sacc[128];
    if (rg == 1) sacc[c4] = acc;
    __syncthreads();
    if (rg == 0) {
        float4 o = sacc[c4];
        acc.x += o.x; acc.y += o.y; acc.z += o.z; acc.w += o.w;
        ((float4*)(part2 + (size_t)blockIdx.x * N_STATE))[c4] = acc;
    }
}

// ---------------------------------------------------------------------------
// Kernel D (fused mstats + reduce2): ONE block x 512 threads.
// ---------------------------------------------------------------------------
__global__ void mstats2_kernel(float* __restrict__ ws, float* __restrict__ out,
                               const float* __restrict__ part2, int nblk)
{
    int tid = threadIdx.x;
    int h   = tid >> 6;       // 0..7 (== wave index)
    int j   = tid & 63;
    const float* pl = ws + WS_PL;
    __shared__ float slf[8], swn[8];

    float lg = 0.f;
    for (int b = j; b < nblk; b += 64) lg += pl[b * N_HEAD + h];
    for (int off = 32; off >= 1; off >>= 1) lg += __shfl_xor(lg, off);

    float p = ws[WS_Q + h * 64 + j] * ws[WS_K + h * 64 + j];
    for (int off = 32; off >= 1; off >>= 1) p += __shfl_xor(p, off);
    p *= 0.125f;

    if (j == 0) {
        float wn = __expf(p);
        out[QK_OFF + (size_t)h * T_TOTAL + KV_LEN] = p;
        slf[h] = lg + wn;
        swn[h] = wn;
    }
    __syncthreads();

    // reduce2: column c = tid
    int c = tid;
    float s = 0.f;
#pragma unroll
    for (int b = 0; b < RB2; ++b) s += part2[(size_t)b * N_STATE + c];
    s += swn[c >> 6] * ws[WS_V + c];
    ws[WS_WV + c] = s / slf[c >> 6];
}

// ---------------------------------------------------------------------------
// Kernel E: out = wv_ @ wo.T + bo. 32 blocks x 256 threads (16 outputs/blk).
// ---------------------------------------------------------------------------
__global__ void outproj_kernel(const float* __restrict__ ws, const float* __restrict__ wo,
                               const float* __restrict__ bo, float* __restrict__ out)
{
    int r    = blockIdx.x * 16 + (threadIdx.x >> 4);
    int lane = threadIdx.x & 15;
    const float4* wr  = (const float4*)(wo + (size_t)r * N_STATE);
    const float4* wv4 = (const float4*)(ws + WS_WV);
    float s = 0.f;
#pragma unroll
    for (int k = 0; k < 8; ++k) {
        int c4 = lane + k * 16;
        float4 a = wv4[c4], b = wr[c4];
        s += a.x * b.x + a.y * b.y + a.z * b.z + a.w * b.w;
    }
    s += __shfl_xor(s, 1);
    s += __shfl_xor(s, 2);
    s += __shfl_xor(s, 4);
    s += __shfl_xor(s, 8);
    if (lane == 0) out[r] = s + bo[r];
}

extern "C" void kernel_launch(void* const* d_in, const int* in_sizes, int n_in,
                              void* d_out, int out_size, void* d_ws, size_t ws_size,
                              hipStream_t stream)
{
    const float* x  = (const float*)d_in[0];
    const float* kc = (const float*)d_in[1];
    const float* vc = (const float*)d_in[2];
    const float* wq = (const float*)d_in[3];
    const float* bq = (const float*)d_in[4];
    const float* wk = (const float*)d_in[5];
    const float* wv = (const float*)d_in[6];
    const float* bv = (const float*)d_in[7];
    const float* wo = (const float*)d_in[8];
    const float* bo = (const float*)d_in[9];
    float* out = (float*)d_out;
    float* ws  = (float*)d_ws;

    float* part  = ws + WS_PART;
    float* part2 = part + (size_t)NBLK * N_STATE;
    float* pl    = ws + WS_PL;

    hipLaunchKernelGGL(proj_kernel, dim3(6), dim3(256), 0, stream,
                       x, wq, bq, wk, wv, bv, ws, out);
    hipLaunchKernelGGL(stream_kernel, dim3(NBLK), dim3(512), 0, stream,
                       kc, vc, ws, out, part, pl);
    hipLaunchKernelGGL(reduce1_kernel, dim3(RB2), dim3(256), 0, stream,
                       part, part2, NBLK / RB2);
    hipLaunchKernelGGL(mstats2_kernel, dim3(1), dim3(512), 0, stream,
                       ws, out, part2, NBLK);
    hipLaunchKernelGGL(outproj_kernel, dim3(32), dim3(256), 0, stream, ws, wo, bo, out);
}